// Round 4
// baseline (923.844 us; speedup 1.0000x reference)
//
#include <hip/hip_runtime.h>
#include <cstddef>

// AdaBP LDPC decoder, MI355X (gfx950) — fully fused.
// Batch columns are independent; one column's state (v2c+c2v = 96 KB) fits in
// one CU's 160 KB LDS. One workgroup (1024 thr) per column runs all T=30
// iterations with __syncthreads() between phases. Output written transposed
// (coalesced) to d_ws, then a tiled transpose kernel produces d_out.

namespace {
constexpr int N  = 4096;
constexpr int M  = 2048;
constexpr int CD = 3;
constexpr int RD = 6;
constexpr int E  = N * CD;   // 12288
constexpr int B  = 128;
constexpr int T  = 30;
constexpr float CLIP    = 15.0f;
constexpr float FEPS    = 1e-6f;
constexpr float MIN_ABS = 6.1180465e-07f;  // -log(tanh(15/2))
constexpr int TPB = 1024;
constexpr int VPT = N / TPB;  // 4 vars per thread
constexpr int CPT = M / TPB;  // 2 checks per thread

// ---- build check -> edge inverse list (each check has exactly RD edges) ----
__global__ __launch_bounds__(256) void k_build(const int* __restrict__ row_idx,
                                               int* __restrict__ cnt,
                                               int* __restrict__ rlist) {
  int e = blockIdx.x * 256 + threadIdx.x;
  if (e < E) {
    int m    = row_idx[e];
    int slot = atomicAdd(&cnt[m], 1);
    rlist[m * RD + slot] = e;  // slot order arbitrary; sums are commutative
  }
}

// ---- the whole decoder for one batch column, LDS-resident ----
__global__ __launch_bounds__(TPB, 4) void k_fused(
    const float* __restrict__ chn,
    const float* __restrict__ gW1, const float* __restrict__ gb1,
    const float* __restrict__ gW2, const float* __restrict__ gb2,
    const float* __restrict__ iW1, const float* __restrict__ ib1,
    const float* __restrict__ iW2, const float* __restrict__ ib2,
    const float* __restrict__ eW1, const float* __restrict__ eb1,
    const float* __restrict__ eW2, const float* __restrict__ eb2,
    const int* __restrict__ rlist, float* __restrict__ outT) {
  __shared__ float v2c_s[E];   // 48 KB
  __shared__ float c2v_s[E];   // 48 KB
  __shared__ float red[32];

  const int tid  = threadIdx.x;
  const int b    = blockIdx.x;   // batch column
  const int wid  = tid >> 6;
  const int lane = tid & 63;

  // zero message state
  for (int i = tid; i < E; i += TPB) { v2c_s[i] = 0.f; c2v_s[i] = 0.f; }

  // load my chn values; accumulate Eng partial
  float ch[VPT];
  float local = 0.f;
#pragma unroll
  for (int i = 0; i < VPT; ++i) {
    int v = tid + i * TPB;
    ch[i] = chn[(size_t)v * B + b];
    local += ch[i] * ch[i];
  }
#pragma unroll
  for (int off = 32; off > 0; off >>= 1) local += __shfl_down(local, off, 64);
  if (lane == 0) red[wid] = local;
  __syncthreads();
  if (tid == 0) {
    float tot = 0.f;
    for (int w = 0; w < 16; ++w) tot += red[w];
    red[16] = tot * (1.f / (float)N);  // Eng
  }
  __syncthreads();
  // waves 0..2 evaluate the three 1-20-1 MLPs (lane j handles hidden unit j)
  if (wid < 3) {
    float Eng = red[16];
    float snr = 10.f * log10f(Eng / (1.f + sqrtf(1.f + Eng)) * 0.5f);
    const float *W1, *b1, *W2, *b2;
    if (wid == 0)      { W1 = gW1; b1 = gb1; W2 = gW2; b2 = gb2; }
    else if (wid == 1) { W1 = iW1; b1 = ib1; W2 = iW2; b2 = ib2; }
    else               { W1 = eW1; b1 = eb1; W2 = eW2; b2 = eb2; }
    float h = 0.f;
    if (lane < 20) h = fmaxf(snr * W1[lane] + b1[lane], 0.f) * W2[lane];
#pragma unroll
    for (int off = 32; off > 0; off >>= 1) h += __shfl_down(h, off, 64);
    if (lane == 0) red[20 + wid] = 1.f / (1.f + expf(-(h + b2[0])));
  }
  __syncthreads();
  const float g   = red[20];
  const float wiv = red[21];
  const float wev = red[22];
  const float omg = 1.f - g;
  float ell[VPT];
#pragma unroll
  for (int i = 0; i < VPT; ++i) ell[i] = wiv * ch[i];

  // preload my checks' edge lists into registers
  int eo[CPT][RD];
#pragma unroll
  for (int i = 0; i < CPT; ++i) {
    int m = tid + i * TPB;
#pragma unroll
    for (int k = 0; k < RD; ++k) eo[i][k] = rlist[m * RD + k];
  }
  __syncthreads();

  for (int t = 0; t < T; ++t) {
    // ---- variable phase: col-LOO (3 contiguous edges), fused out[t-1] ----
#pragma unroll
    for (int i = 0; i < VPT; ++i) {
      int v    = tid + i * TPB;
      int base = v * CD;
      float w0 = wev * c2v_s[base];
      float w1 = wev * c2v_s[base + 1];
      float w2 = wev * c2v_s[base + 2];
      float es = ell[i] + w0 + w1 + w2;
      if (t > 0) outT[((size_t)b * T + (t - 1)) * N + v] = es;
      v2c_s[base]     = omg * v2c_s[base]     + g * (es - w0);
      v2c_s[base + 1] = omg * v2c_s[base + 1] + g * (es - w1);
      v2c_s[base + 2] = omg * v2c_s[base + 2] + g * (es - w2);
    }
    __syncthreads();
    // ---- check phase: row-LOO parity + log-tanh sums ----
#pragma unroll
    for (int i = 0; i < CPT; ++i) {
      float lam[RD], lt[RD];
      int neg = 0;
      float lts = 0.f;
#pragma unroll
      for (int k = 0; k < RD; ++k) {
        float x = v2c_s[eo[i][k]];
        float l = fminf(fmaxf(x, -CLIP), CLIP);
        lam[k]  = l;
        neg += (l < 0.f) ? 1 : 0;
        float al = fmaxf(fabsf(l), MIN_ABS);
        float lte;
        if (al > 0.5f) {
          float Ex = expf(-al);
          lte = log1pf(-Ex) - log1pf(Ex);
        } else {
          float em = expm1f(-al);  // accurate near 0
          lte = logf(-em) - logf(2.f + em);
        }
        lt[k] = lte;
        lts  += lte;
      }
#pragma unroll
      for (int k = 0; k < RD; ++k) {
        int   c   = neg - ((lam[k] < 0.f) ? 1 : 0);
        float amp = lts - lt[k];  // < 0
        // 2*atanh(e^amp * (1-eps)) via expm1 (stable near amp->0-)
        float ea   = expf(amp);
        float em1  = expm1f(amp);
        float num  = 2.f + em1 - FEPS * ea;
        float den  = FEPS * ea - em1;
        float cnew = logf(num / den);
        if (c & 1) cnew = -cnew;
        int idx    = eo[i][k];
        c2v_s[idx] = omg * c2v_s[idx] + g * cnew;
      }
    }
    __syncthreads();
  }
  // ---- final output row: out[T-1] = ell + full col sum ----
#pragma unroll
  for (int i = 0; i < VPT; ++i) {
    int v    = tid + i * TPB;
    int base = v * CD;
    float s  = wev * (c2v_s[base] + c2v_s[base + 1] + c2v_s[base + 2]);
    outT[((size_t)b * T + (T - 1)) * N + v] = ell[i] + s;
  }
}

// ---- transpose out_T[b][t][v] -> out[t][v][b], tiled through LDS ----
__global__ __launch_bounds__(256) void k_tr(const float* __restrict__ outT,
                                            float* __restrict__ out) {
  __shared__ float tile[128 * 65];  // [b][v-tile], padded
  int t   = blockIdx.y;
  int v0  = blockIdx.x * 64;
  int tid = threadIdx.x;
#pragma unroll
  for (int r = 0; r < 32; ++r) {
    int bb = r * 4 + (tid >> 6);
    int v  = tid & 63;
    tile[bb * 65 + v] = outT[((size_t)bb * T + t) * N + v0 + v];
  }
  __syncthreads();
#pragma unroll
  for (int r = 0; r < 32; ++r) {
    int v  = r * 2 + (tid >> 7);
    int bb = tid & 127;
    // out is never re-read: non-temporal store keeps it out of L2
    __builtin_nontemporal_store(tile[bb * 65 + v],
                                &out[((size_t)t * N + v0 + v) * B + bb]);
  }
}

}  // namespace

extern "C" void kernel_launch(void* const* d_in, const int* in_sizes, int n_in,
                              void* d_out, int out_size, void* d_ws,
                              size_t ws_size, hipStream_t stream) {
  const float* chn = (const float*)d_in[0];
  const float* gW1 = (const float*)d_in[1];
  const float* gb1 = (const float*)d_in[2];
  const float* gW2 = (const float*)d_in[3];
  const float* gb2 = (const float*)d_in[4];
  const float* iW1 = (const float*)d_in[5];
  const float* ib1 = (const float*)d_in[6];
  const float* iW2 = (const float*)d_in[7];
  const float* ib2 = (const float*)d_in[8];
  const float* eW1 = (const float*)d_in[9];
  const float* eb1 = (const float*)d_in[10];
  const float* eW2 = (const float*)d_in[11];
  const float* eb2 = (const float*)d_in[12];
  const int* row_idx = (const int*)d_in[13];
  // d_in[14] (col_idx) = repeat(arange(N),3) by construction -> implicit.
  float* out = (float*)d_out;

  // workspace layout
  float* outT  = (float*)d_ws;                      // B*T*N floats (63 MB)
  int*   cnt   = (int*)(outT + (size_t)B * T * N);  // M ints
  int*   rlist = cnt + M;                           // E ints

  hipMemsetAsync(cnt, 0, M * sizeof(int), stream);
  k_build<<<(E + 255) / 256, 256, 0, stream>>>(row_idx, cnt, rlist);
  k_fused<<<B, TPB, 0, stream>>>(chn, gW1, gb1, gW2, gb2, iW1, ib1, iW2, ib2,
                                 eW1, eb1, eW2, eb2, rlist, outT);
  dim3 tg(N / 64, T);
  k_tr<<<tg, 256, 0, stream>>>(outT, out);
}

// Round 9
// 295.890 us; speedup vs baseline: 3.1223x; 3.1223x over previous
//
#include <hip/hip_runtime.h>
#include <cstddef>

// AdaBP LDPC decoder, MI355X (gfx950) — fully fused, hardware-trans math.
// One workgroup per batch column; column state (v2c+c2v = 96 KB) in LDS;
// all T=30 iterations in one kernel. Check-phase transcendentals rewritten
// onto raw v_exp/v_log/v_rcp with branchless poly/log selects (round 4 showed
// expm1f/log1pf software routines + divergence made the kernel VALU-bound).

namespace {
constexpr int N  = 4096;
constexpr int M  = 2048;
constexpr int CD = 3;
constexpr int RD = 6;
constexpr int E  = N * CD;   // 12288
constexpr int B  = 128;
constexpr int T  = 30;
constexpr float CLIP    = 15.0f;
constexpr float FEPS    = 1e-6f;
constexpr float MIN_ABS = 6.1180465e-07f;  // -log(tanh(15/2))
constexpr int TPB = 1024;
constexpr int VPT = N / TPB;  // 4 vars per thread
constexpr int CPT = M / TPB;  // 2 checks per thread

// ---- build check -> edge inverse list (each check has exactly RD edges) ----
__global__ __launch_bounds__(256) void k_build(const int* __restrict__ row_idx,
                                               int* __restrict__ cnt,
                                               int* __restrict__ rlist) {
  int e = blockIdx.x * 256 + threadIdx.x;
  if (e < E) {
    int m    = row_idx[e];
    int slot = atomicAdd(&cnt[m], 1);
    rlist[m * RD + slot] = e;  // slot order arbitrary; sums are commutative
  }
}

// ---- the whole decoder for one batch column, LDS-resident ----
__global__ __launch_bounds__(TPB, 4) void k_fused(
    const float* __restrict__ chn,
    const float* __restrict__ gW1, const float* __restrict__ gb1,
    const float* __restrict__ gW2, const float* __restrict__ gb2,
    const float* __restrict__ iW1, const float* __restrict__ ib1,
    const float* __restrict__ iW2, const float* __restrict__ ib2,
    const float* __restrict__ eW1, const float* __restrict__ eb1,
    const float* __restrict__ eW2, const float* __restrict__ eb2,
    const int* __restrict__ rlist, float* __restrict__ outT) {
  __shared__ float v2c_s[E];   // 48 KB
  __shared__ float c2v_s[E];   // 48 KB
  __shared__ float red[32];

  const int tid  = threadIdx.x;
  const int b    = blockIdx.x;   // batch column
  const int wid  = tid >> 6;
  const int lane = tid & 63;

  // zero message state
  for (int i = tid; i < E; i += TPB) { v2c_s[i] = 0.f; c2v_s[i] = 0.f; }

  // load my chn values; accumulate Eng partial
  float ch[VPT];
  float local = 0.f;
#pragma unroll
  for (int i = 0; i < VPT; ++i) {
    int v = tid + i * TPB;
    ch[i] = chn[(size_t)v * B + b];
    local += ch[i] * ch[i];
  }
#pragma unroll
  for (int off = 32; off > 0; off >>= 1) local += __shfl_down(local, off, 64);
  if (lane == 0) red[wid] = local;
  __syncthreads();
  if (tid == 0) {
    float tot = 0.f;
    for (int w = 0; w < 16; ++w) tot += red[w];
    red[16] = tot * (1.f / (float)N);  // Eng
  }
  __syncthreads();
  // waves 0..2 evaluate the three 1-20-1 MLPs (lane j handles hidden unit j)
  if (wid < 3) {
    float Eng = red[16];
    float snr = 10.f * log10f(Eng / (1.f + sqrtf(1.f + Eng)) * 0.5f);
    const float *W1, *b1, *W2, *b2;
    if (wid == 0)      { W1 = gW1; b1 = gb1; W2 = gW2; b2 = gb2; }
    else if (wid == 1) { W1 = iW1; b1 = ib1; W2 = iW2; b2 = ib2; }
    else               { W1 = eW1; b1 = eb1; W2 = eW2; b2 = eb2; }
    float h = 0.f;
    if (lane < 20) h = fmaxf(snr * W1[lane] + b1[lane], 0.f) * W2[lane];
#pragma unroll
    for (int off = 32; off > 0; off >>= 1) h += __shfl_down(h, off, 64);
    if (lane == 0) red[20 + wid] = 1.f / (1.f + expf(-(h + b2[0])));
  }
  __syncthreads();
  const float g   = red[20];
  const float wiv = red[21];
  const float wev = red[22];
  const float omg = 1.f - g;
  float ell[VPT];
#pragma unroll
  for (int i = 0; i < VPT; ++i) ell[i] = wiv * ch[i];

  // preload my checks' edge lists into registers
  int eo[CPT][RD];
#pragma unroll
  for (int i = 0; i < CPT; ++i) {
    int m = tid + i * TPB;
#pragma unroll
    for (int k = 0; k < RD; ++k) eo[i][k] = rlist[m * RD + k];
  }
  __syncthreads();

  for (int t = 0; t < T; ++t) {
    // ---- variable phase: col-LOO (3 contiguous edges), fused out[t-1] ----
#pragma unroll
    for (int i = 0; i < VPT; ++i) {
      int v    = tid + i * TPB;
      int base = v * CD;
      float w0 = wev * c2v_s[base];
      float w1 = wev * c2v_s[base + 1];
      float w2 = wev * c2v_s[base + 2];
      float es = ell[i] + w0 + w1 + w2;
      if (t > 0) outT[((size_t)b * T + (t - 1)) * N + v] = es;
      v2c_s[base]     = omg * v2c_s[base]     + g * (es - w0);
      v2c_s[base + 1] = omg * v2c_s[base + 1] + g * (es - w1);
      v2c_s[base + 2] = omg * v2c_s[base + 2] + g * (es - w2);
    }
    __syncthreads();
    // ---- check phase: row-LOO parity + log-tanh sums (HW trans ops) ----
#pragma unroll
    for (int i = 0; i < CPT; ++i) {
      float lt[RD];
      int nmask = 0;
      int neg = 0;
      float lts = 0.f;
#pragma unroll
      for (int k = 0; k < RD; ++k) {
        float x = v2c_s[eo[i][k]];
        float l = fminf(fmaxf(x, -CLIP), CLIP);
        int   nb = (l < 0.f) ? 1 : 0;
        neg   += nb;
        nmask |= nb << k;
        float al = fmaxf(fabsf(l), MIN_ABS);
        // lt = log(tanh(al/2)); tanh(al/2) = (ea-1)/(ea+1), u = 1-tanh = 2/(ea+1)
        float ea = __expf(al);
        float r  = __builtin_amdgcn_rcpf(ea + 1.f);
        float u  = 2.f * r;
        // u < 0.04 (saturated): log(1-u) = -(u + u^2/2 + u^3/3), err < 1e-6
        float ltp = -u * fmaf(u, fmaf(u, 0.33333333f, 0.5f), 1.f);
        float ltl = __logf((ea - 1.f) * r);
        float lte = (u < 0.04f) ? ltp : ltl;
        lt[k] = lte;
        lts  += lte;
      }
#pragma unroll
      for (int k = 0; k < RD; ++k) {
        int   c   = neg - ((nmask >> k) & 1);
        float amp = lts - lt[k];  // < 0
        // c_new = 2*atanh(e^amp * (1-eps));  em = expm1(amp) branchless:
        float ea2 = __expf(amp);
        float emp = amp * fmaf(amp, fmaf(amp, 0.16666667f, 0.5f), 1.f);
        float em  = (amp > -0.04f) ? emp : (ea2 - 1.f);
        float den = fmaf(FEPS, ea2, -em);        // 1 - x  (> 0)
        float num = fmaf(-FEPS, ea2, 2.f + em);  // 1 + x
        float cnew = __logf(num * __builtin_amdgcn_rcpf(den));
        if (c & 1) cnew = -cnew;
        int idx    = eo[i][k];
        c2v_s[idx] = omg * c2v_s[idx] + g * cnew;
      }
    }
    __syncthreads();
  }
  // ---- final output row: out[T-1] = ell + full col sum ----
#pragma unroll
  for (int i = 0; i < VPT; ++i) {
    int v    = tid + i * TPB;
    int base = v * CD;
    float s  = wev * (c2v_s[base] + c2v_s[base + 1] + c2v_s[base + 2]);
    outT[((size_t)b * T + (T - 1)) * N + v] = ell[i] + s;
  }
}

// ---- transpose out_T[b][t][v] -> out[t][v][b], tiled through LDS ----
__global__ __launch_bounds__(256) void k_tr(const float* __restrict__ outT,
                                            float* __restrict__ out) {
  __shared__ float tile[128 * 65];  // [b][v-tile], padded
  int t   = blockIdx.y;
  int v0  = blockIdx.x * 64;
  int tid = threadIdx.x;
#pragma unroll
  for (int r = 0; r < 32; ++r) {
    int bb = r * 4 + (tid >> 6);
    int v  = tid & 63;
    tile[bb * 65 + v] = outT[((size_t)bb * T + t) * N + v0 + v];
  }
  __syncthreads();
#pragma unroll
  for (int r = 0; r < 32; ++r) {
    int v  = r * 2 + (tid >> 7);
    int bb = tid & 127;
    // out is never re-read: non-temporal store keeps it out of L2
    __builtin_nontemporal_store(tile[bb * 65 + v],
                                &out[((size_t)t * N + v0 + v) * B + bb]);
  }
}

}  // namespace

extern "C" void kernel_launch(void* const* d_in, const int* in_sizes, int n_in,
                              void* d_out, int out_size, void* d_ws,
                              size_t ws_size, hipStream_t stream) {
  const float* chn = (const float*)d_in[0];
  const float* gW1 = (const float*)d_in[1];
  const float* gb1 = (const float*)d_in[2];
  const float* gW2 = (const float*)d_in[3];
  const float* gb2 = (const float*)d_in[4];
  const float* iW1 = (const float*)d_in[5];
  const float* ib1 = (const float*)d_in[6];
  const float* iW2 = (const float*)d_in[7];
  const float* ib2 = (const float*)d_in[8];
  const float* eW1 = (const float*)d_in[9];
  const float* eb1 = (const float*)d_in[10];
  const float* eW2 = (const float*)d_in[11];
  const float* eb2 = (const float*)d_in[12];
  const int* row_idx = (const int*)d_in[13];
  // d_in[14] (col_idx) = repeat(arange(N),3) by construction -> implicit.
  float* out = (float*)d_out;

  // workspace layout
  float* outT  = (float*)d_ws;                      // B*T*N floats (63 MB)
  int*   cnt   = (int*)(outT + (size_t)B * T * N);  // M ints
  int*   rlist = cnt + M;                           // E ints

  hipMemsetAsync(cnt, 0, M * sizeof(int), stream);
  k_build<<<(E + 255) / 256, 256, 0, stream>>>(row_idx, cnt, rlist);
  k_fused<<<B, TPB, 0, stream>>>(chn, gW1, gb1, gW2, gb2, iW1, ib1, iW2, ib2,
                                 eW1, eb1, eW2, eb2, rlist, outT);
  dim3 tg(N / 64, T);
  k_tr<<<tg, 256, 0, stream>>>(outT, out);
}